// Round 9
// baseline (67.997 us; speedup 1.0000x reference)
//
#include <hip/hip_runtime.h>

#define B_    4
#define CIN_  64
#define H_    128
#define W_    128
#define COUT_ 64
#define HW    (H_*W_)
#define KPOS  576

typedef __attribute__((ext_vector_type(8))) short bf16x8;
typedef __attribute__((ext_vector_type(4))) short bf16x4;
typedef __attribute__((ext_vector_type(4))) float f32x4;
typedef __attribute__((ext_vector_type(4))) _Float16 f16x4;

static __device__ __forceinline__ unsigned short f2bf(float f) {
    union { float f; unsigned u; } a; a.f = f;
    unsigned r = a.u + 0x7fffu + ((a.u >> 16) & 1u);   // RNE
    return (unsigned short)(r >> 16);
}
static __device__ __forceinline__ float bfl(unsigned u) {   // low bf16 -> f32
    union { unsigned x; float f; } a; a.x = u << 16; return a.f;
}
static __device__ __forceinline__ float bfh(unsigned u) {   // high bf16 -> f32
    union { unsigned x; float f; } a; a.x = u & 0xffff0000u; return a.f;
}
static __device__ __forceinline__ unsigned cvt_pk_bf16(float lo, float hi) {
    unsigned r;
    asm("v_cvt_pk_bf16_f32 %0, %1, %2" : "=v"(r) : "v"(lo), "v"(hi));
    return r;
}

#define XT_USHORTS 4194304                       // B*HW*64 NHWC bf16 image
#define WP_USHORTS 36864                         // wt2[k][p][co][32c]
#define META_CNT   (B_*9*HW)                     // 589824
#define OFFS_BYTE  ((XT_USHORTS + WP_USHORTS) * 2)        // 8462336
#define WTS_BYTE   (OFFS_BYTE + META_CNT * 4)             // 10821632
#define WS_NEED3   ((size_t)(WTS_BYTE + META_CNT * 8))    // ~15.5 MB

// ================= fused prep: xpose | meta | weight in one launch =========
__global__ __launch_bounds__(256)
void prep_all(const float* __restrict__ x,
              const float* __restrict__ offset,
              const float* __restrict__ mask,
              const float* __restrict__ w,
              unsigned short* __restrict__ xT,
              unsigned short* __restrict__ wt,
              unsigned* __restrict__ mOffs,
              f16x4* __restrict__ mWts)
{
    const int bid = blockIdx.x;
    const int t   = threadIdx.x;

    if (bid < 512) {
        // ---- x NCHW f32 -> NHWC bf16 (one (b,y) row per block) ----
        __shared__ unsigned short ld[64 * 132];
        const int b = bid >> 7;
        const int y = bid & 127;
        const float* src = x + (size_t)b * 64 * HW + y * W_;
        #pragma unroll
        for (int i = 0; i < 8; ++i) {
            const int e4 = (t + i * 256) * 4;
            const int c  = e4 >> 7;
            const int x0 = e4 & 127;
            const float4 v = *(const float4*)(src + (size_t)c * HW + x0);
            unsigned short* d = &ld[c * 132 + x0];
            d[0] = f2bf(v.x); d[1] = f2bf(v.y); d[2] = f2bf(v.z); d[3] = f2bf(v.w);
        }
        __syncthreads();
        unsigned short* dst = xT + ((size_t)b * HW + (size_t)y * W_) * 64;
        #pragma unroll
        for (int i = 0; i < 4; ++i) {
            const int o    = (t + i * 256) * 8;
            const int xcol = o >> 6;
            const int c0   = o & 63;
            union { bf16x8 v; unsigned short u[8]; } pk;
            #pragma unroll
            for (int j = 0; j < 8; ++j) pk.u[j] = ld[(c0 + j) * 132 + xcol];
            *(bf16x8*)(dst + o) = pk.v;
        }
    } else if (bid < 2816) {
        // ---- sampling metadata per (b,tap,pixel) ----
        const int i  = (bid - 512) * 256 + t;
        const int gp = i & (HW - 1);
        const int bk = i >> 14;              // b*9 + k
        const int b  = bk / 9;
        const int k  = bk - b * 9;
        const int ho = gp >> 7, wo = gp & 127;
        const float dy = offset[(size_t)(b * 18 + 2 * k) * HW + gp];
        const float dx = offset[(size_t)(b * 18 + 2 * k + 1) * HW + gp];
        const float mm = mask[(size_t)bk * HW + gp];
        const float py  = dy + (float)(k / 3) + (float)(ho - 1);   // PAD=1
        const float pxx = dx + (float)(k % 3) + (float)(wo - 1);
        const float y0f = floorf(py), x0f = floorf(pxx);
        const float wy = py - y0f, wx = pxx - x0f;
        const int y0 = (int)y0f, x0 = (int)x0f;
        const int y1 = y0 + 1,  x1 = x0 + 1;
        const bool vy0 = (y0 >= 0) & (y0 < H_), vy1 = (y1 >= 0) & (y1 < H_);
        const bool vx0 = (x0 >= 0) & (x0 < W_), vx1 = (x1 >= 0) & (x1 < W_);
        const int cy0 = min(max(y0, 0), H_-1), cy1 = min(max(y1, 0), H_-1);
        const int cx0 = min(max(x0, 0), W_-1), cx1 = min(max(x1, 0), W_-1);
        mOffs[i] = (unsigned)cy0 | ((unsigned)cy1 << 8)
                 | ((unsigned)cx0 << 16) | ((unsigned)cx1 << 24);
        f16x4 wv;
        wv[0] = (_Float16)((vy0 && vx0) ? (1.f - wy) * (1.f - wx) * mm : 0.f);
        wv[1] = (_Float16)((vy0 && vx1) ? (1.f - wy) * wx * mm         : 0.f);
        wv[2] = (_Float16)((vy1 && vx0) ? wy * (1.f - wx) * mm         : 0.f);
        wv[3] = (_Float16)((vy1 && vx1) ? wy * wx * mm                 : 0.f);
        mWts[i] = wv;
    } else {
        // ---- weight -> bf16: wt2[k][p][co][c32], c = p*32+c32 ----
        const int i = (bid - 2816) * 256 + t;
        if (i < 9 * 2 * 64 * 32) {
            const int k   = i >> 12;
            const int r   = i & 4095;
            const int p   = r >> 11;
            const int r2  = r & 2047;
            const int co  = r2 >> 5;
            const int c32 = r2 & 31;
            const int c   = p * 32 + c32;
            wt[i] = f2bf(w[co * KPOS + c * 9 + k]);
        }
    }
}

// ================= main: K-split waves, 32 waves/CU target ================
// Grid 2048 blocks (8/CU). Block = 32 px x 64 cout: 2 px-groups x 2 ch-splits.
// Each wave: 16 px x 32 ch (its K half) x 9 taps, zero-LDS main loop
// (bilinear output IS the MFMA A-fragment); K-halves summed via LDS at end.
// Latency hidden by TLP (6-8 waves/SIMD), not per-wave MLP.
__global__ __launch_bounds__(256, 6)
void dcn_ksplit(const unsigned short* __restrict__ xT,
                const unsigned* __restrict__ mOffs,
                const f16x4* __restrict__ mWts,
                const float* __restrict__ bias,
                const unsigned short* __restrict__ wt2,
                float* __restrict__ out)
{
    __shared__ float red[2][16][68];     // [px-group][px][co] partial sums

    const int t    = threadIdx.x;
    const int bid  = blockIdx.x;
    const int wk   = ((bid & 7) << 8) | (bid >> 3);   // 2048 = 8 XCD * 256
    const int b    = wk >> 9;
    const int rem  = wk & 511;
    const int ho   = rem >> 2;
    const int qx   = rem & 3;            // 32-px strip within row
    const int wv   = t >> 6;
    const int pg   = wv >> 1;            // px group 0/1
    const int sp   = wv & 1;             // channel split 0/1
    const int lane = t & 63;
    const int pxl  = lane & 15;          // pixel = MFMA A/D row
    const int oct  = lane >> 4;          // k-frag oct
    const int cho  = sp * 32 + oct * 8;  // channel offset in NHWC row

    f32x4 acc[4];
    #pragma unroll
    for (int i = 0; i < 4; ++i) acc[i] = (f32x4){0.f, 0.f, 0.f, 0.f};

    const unsigned short* xTb = xT + (size_t)b * HW * 64;
    const int gp    = ho * W_ + qx * 32 + pg * 16 + pxl;
    const int mbase = (b * 9) << 14;

    unsigned mO_c = mOffs[mbase + gp];
    f16x4    mW_c = mWts [mbase + gp];

    #pragma unroll
    for (int k = 0; k < 9; ++k) {
        unsigned mO_n = 0; f16x4 mW_n = {};
        if (k < 8) {
            const int mi = mbase + ((k + 1) << 14) + gp;
            mO_n = mOffs[mi];
            mW_n = mWts[mi];
        }

        // ---- decode + gather: this lane's pixel, 4 corners, its ch-oct ----
        const unsigned pk = mO_c;
        const int y0 = (pk & 255) << 7,  y1 = ((pk >> 8) & 255) << 7;
        const int x0 = (pk >> 16) & 255, x1 = (int)(pk >> 24);
        const bf16x8 c00 = *(const bf16x8*)(xTb + ((y0 | x0) << 6) + cho);
        const bf16x8 c01 = *(const bf16x8*)(xTb + ((y0 | x1) << 6) + cho);
        const bf16x8 c10 = *(const bf16x8*)(xTb + ((y1 | x0) << 6) + cho);
        const bf16x8 c11 = *(const bf16x8*)(xTb + ((y1 | x1) << 6) + cho);

        // ---- B fragments for this K half (L1-hot, 1KB/wave-inst) ----
        const unsigned short* wp = wt2 + (k * 2 + sp) * 2048 + (lane & 15) * 32 + oct * 8;
        bf16x8 bf0 = *(const bf16x8*)(wp);
        bf16x8 bf1 = *(const bf16x8*)(wp + 512);
        bf16x8 bf2 = *(const bf16x8*)(wp + 1024);
        bf16x8 bf3 = *(const bf16x8*)(wp + 1536);

        const float w0 = (float)mW_c[0];
        const float w1 = (float)mW_c[1];
        const float w2 = (float)mW_c[2];
        const float w3 = (float)mW_c[3];

        // ---- bilinear combine -> A fragment (8 ch = this lane's k-oct) ----
        union { bf16x8 v; unsigned u[4]; } a;
        {
            const unsigned* u0 = (const unsigned*)&c00;
            const unsigned* u1 = (const unsigned*)&c01;
            const unsigned* u2 = (const unsigned*)&c10;
            const unsigned* u3 = (const unsigned*)&c11;
            #pragma unroll
            for (int j = 0; j < 4; ++j) {
                const float lo = w0*bfl(u0[j]) + w1*bfl(u1[j])
                               + w2*bfl(u2[j]) + w3*bfl(u3[j]);
                const float hi = w0*bfh(u0[j]) + w1*bfh(u1[j])
                               + w2*bfh(u2[j]) + w3*bfh(u3[j]);
                a.u[j] = cvt_pk_bf16(lo, hi);
            }
        }

        // ---- 4 MFMAs for this tap's K=32 half ----
        acc[0] = __builtin_amdgcn_mfma_f32_16x16x32_bf16(a.v, bf0, acc[0], 0, 0, 0);
        acc[1] = __builtin_amdgcn_mfma_f32_16x16x32_bf16(a.v, bf1, acc[1], 0, 0, 0);
        acc[2] = __builtin_amdgcn_mfma_f32_16x16x32_bf16(a.v, bf2, acc[2], 0, 0, 0);
        acc[3] = __builtin_amdgcn_mfma_f32_16x16x32_bf16(a.v, bf3, acc[3], 0, 0, 0);

        mO_c = mO_n;
        mW_c = mW_n;
    }

    // ---- K-half reduction via LDS, then epilogue ----
    const int row0 = (lane >> 4) * 4;       // D rows this lane holds
    const int col  = lane & 15;             // D col within nt tile
    if (sp == 0) {
        #pragma unroll
        for (int nt = 0; nt < 4; ++nt)
            #pragma unroll
            for (int j = 0; j < 4; ++j)
                red[pg][row0 + j][nt * 16 + col] = acc[nt][j];
    }
    __syncthreads();
    if (sp == 1) {
        #pragma unroll
        for (int nt = 0; nt < 4; ++nt) {
            const int co = nt * 16 + col;
            const float bb = bias[co];
            float4 r;
            r.x = acc[nt][0] + red[pg][row0 + 0][co] + bb;
            r.y = acc[nt][1] + red[pg][row0 + 1][co] + bb;
            r.z = acc[nt][2] + red[pg][row0 + 2][co] + bb;
            r.w = acc[nt][3] + red[pg][row0 + 3][co] + bb;
            *(float4*)&out[(((size_t)b * COUT_ + co) * H_ + ho) * W_
                           + qx * 32 + pg * 16 + row0] = r;
        }
    }
}

// ================= fallback path (ws too small): R4 kernels =================
__global__ __launch_bounds__(256)
void xpose_bf16(const float* __restrict__ x, unsigned short* __restrict__ xT)
{
    __shared__ unsigned short ld[64 * 132];
    const int t   = threadIdx.x;
    const int blk = blockIdx.x;
    const int b   = blk >> 7;
    const int y   = blk & 127;
    const float* src = x + (size_t)b * 64 * HW + y * W_;
    #pragma unroll
    for (int i = 0; i < 8; ++i) {
        const int e4 = (t + i * 256) * 4;
        const int c  = e4 >> 7;
        const int x0 = e4 & 127;
        const float4 v = *(const float4*)(src + (size_t)c * HW + x0);
        unsigned short* d = &ld[c * 132 + x0];
        d[0] = f2bf(v.x); d[1] = f2bf(v.y); d[2] = f2bf(v.z); d[3] = f2bf(v.w);
    }
    __syncthreads();
    unsigned short* dst = xT + ((size_t)b * HW + (size_t)y * W_) * 64;
    #pragma unroll
    for (int i = 0; i < 4; ++i) {
        const int o    = (t + i * 256) * 8;
        const int xcol = o >> 6;
        const int c0   = o & 63;
        union { bf16x8 v; unsigned short u[8]; } pk;
        #pragma unroll
        for (int j = 0; j < 8; ++j) pk.u[j] = ld[(c0 + j) * 132 + xcol];
        *(bf16x8*)(dst + o) = pk.v;
    }
}

__global__ void prep_weight_fb(const float* __restrict__ w,
                               unsigned short* __restrict__ wt)
{
    const int i = blockIdx.x * 256 + threadIdx.x;
    if (i >= 9 * 64 * 64) return;
    const int k  = i >> 12;
    const int r  = i & 4095;
    const int co = r >> 6;
    const int c  = r & 63;
    wt[i] = f2bf(w[co * KPOS + c * 9 + k]);
}

__global__ __launch_bounds__(256, 4)
void dcn_mfma_nhwc(const unsigned short* __restrict__ xT,
                   const float* __restrict__ offset,
                   const float* __restrict__ mask,
                   const float* __restrict__ bias,
                   const unsigned short* __restrict__ wprep,
                   float* __restrict__ out)
{
    __shared__ unsigned short vP[2][64][72];
    __shared__ unsigned short Wk[2][64][72];
    const int t   = threadIdx.x;
    const int bid = blockIdx.x;
    const int wk  = ((bid & 7) << 7) | (bid >> 3);
    const int xh  = wk & 1;
    const int ho  = (wk >> 1) & 127;
    const int b   = wk >> 8;
    const int cq  = t >> 6;
    const int lane = t & 63;
    const int px_sub = lane >> 4;
    const int c4     = lane & 15;
    f32x4 acc[4];
    #pragma unroll
    for (int i = 0; i < 4; ++i) acc[i] = (f32x4){0.f, 0.f, 0.f, 0.f};
    const unsigned short* xTb = xT + (size_t)b * HW * 64;

    auto stage = [&](int k, int s) {
        int   idxs[4][4];
        float wts [4][4];
        #pragma unroll
        for (int it = 0; it < 4; ++it) {
            const int pl = (cq << 4) | (it << 2) | px_sub;
            const int wo = xh * 64 + pl;
            const int obase = ((b * 18 + 2 * k) * H_ + ho) * W_ + wo;
            const float dy = offset[obase];
            const float dx = offset[obase + HW];
            const float mm = mask[((b * 9 + k) * H_ + ho) * W_ + wo];
            const float py  = dy + (float)(k / 3) + (float)(ho - 1);
            const float pxx = dx + (float)(k % 3) + (float)(wo - 1);
            const float y0f = floorf(py), x0f = floorf(pxx);
            const float wy = py - y0f, wx = pxx - x0f;
            const int y0 = (int)y0f, x0 = (int)x0f;
            const int y1 = y0 + 1,  x1 = x0 + 1;
            const bool vy0 = (y0 >= 0) & (y0 < H_), vy1 = (y1 >= 0) & (y1 < H_);
            const bool vx0 = (x0 >= 0) & (x0 < W_), vx1 = (x1 >= 0) & (x1 < W_);
            const int cy0 = min(max(y0, 0), H_-1), cy1 = min(max(y1, 0), H_-1);
            const int cx0 = min(max(x0, 0), W_-1), cx1 = min(max(x1, 0), W_-1);
            idxs[it][0] = (cy0 * W_ + cx0) << 6;
            idxs[it][1] = (cy0 * W_ + cx1) << 6;
            idxs[it][2] = (cy1 * W_ + cx0) << 6;
            idxs[it][3] = (cy1 * W_ + cx1) << 6;
            wts[it][0] = (vy0 && vx0) ? (1.f - wy) * (1.f - wx) * mm : 0.f;
            wts[it][1] = (vy0 && vx1) ? (1.f - wy) * wx * mm         : 0.f;
            wts[it][2] = (vy1 && vx0) ? wy * (1.f - wx) * mm         : 0.f;
            wts[it][3] = (vy1 && vx1) ? wy * wx * mm                 : 0.f;
        }
        bf16x4 cr[4][4];
        #pragma unroll
        for (int it = 0; it < 4; ++it)
            #pragma unroll
            for (int cn = 0; cn < 4; ++cn)
                cr[it][cn] = *(const bf16x4*)(xTb + idxs[it][cn] + (c4 << 2));
        #pragma unroll
        for (int q = 0; q < 2; ++q) {
            const int j  = q * 2048 + t * 8;
            *(bf16x8*)&Wk[s][j >> 6][j & 63] = *(const bf16x8*)(wprep + k * 4096 + j);
        }
        #pragma unroll
        for (int it = 0; it < 4; ++it) {
            const int pl = (cq << 4) | (it << 2) | px_sub;
            union { bf16x4 v; unsigned short u[4]; } pk;
            #pragma unroll
            for (int j = 0; j < 4; ++j) {
                union { short s; unsigned short u; } s0{cr[it][0][j]}, s1{cr[it][1][j]},
                                                     s2{cr[it][2][j]}, s3{cr[it][3][j]};
                const float v = wts[it][0] * bfl(s0.u) + wts[it][1] * bfl(s1.u)
                              + wts[it][2] * bfl(s2.u) + wts[it][3] * bfl(s3.u);
                pk.u[j] = f2bf(v);
            }
            *(bf16x4*)&vP[s][pl][c4 << 2] = pk.v;
        }
    };
    auto domfma = [&](int s) {
        const int ra = cq * 16 + (lane & 15);
        const int kc = (lane >> 4) * 8;
        #pragma unroll
        for (int ks = 0; ks < 2; ++ks) {
            const int kcol = ks * 32 + kc;
            const bf16x8 a = *(const bf16x8*)&vP[s][ra][kcol];
            #pragma unroll
            for (int nt = 0; nt < 4; ++nt) {
                const bf16x8 bb = *(const bf16x8*)&Wk[s][nt * 16 + (lane & 15)][kcol];
                acc[nt] = __builtin_amdgcn_mfma_f32_16x16x32_bf16(a, bb, acc[nt], 0, 0, 0);
            }
        }
    };
    stage(0, 0);
    __syncthreads();
    for (int k = 0; k < 9; ++k) {
        const int s = k & 1;
        if (k < 8) stage(k + 1, s ^ 1);
        domfma(s);
        __syncthreads();
    }
    const int px0 = cq * 16 + (lane >> 4) * 4;
    #pragma unroll
    for (int nt = 0; nt < 4; ++nt) {
        const int co = nt * 16 + (lane & 15);
        const float bb = bias[co];
        float4 r;
        r.x = acc[nt][0] + bb;
        r.y = acc[nt][1] + bb;
        r.z = acc[nt][2] + bb;
        r.w = acc[nt][3] + bb;
        *(float4*)&out[(((size_t)b * COUT_ + co) * H_ + ho) * W_ + xh * 64 + px0] = r;
    }
}

extern "C" void kernel_launch(void* const* d_in, const int* in_sizes, int n_in,
                              void* d_out, int out_size, void* d_ws, size_t ws_size,
                              hipStream_t stream)
{
    const float* x      = (const float*)d_in[0];
    const float* offset = (const float*)d_in[1];
    const float* mask   = (const float*)d_in[2];
    const float* weight = (const float*)d_in[3];
    const float* bias   = (const float*)d_in[4];
    float* out = (float*)d_out;

    dim3 block(256);

    unsigned short* xT    = (unsigned short*)d_ws;
    unsigned short* wprep = xT + XT_USHORTS;

    if (ws_size >= WS_NEED3) {
        unsigned* mOffs = (unsigned*)((char*)d_ws + OFFS_BYTE);
        f16x4*    mWts  = (f16x4*)  ((char*)d_ws + WTS_BYTE);
        prep_all<<<dim3(2960), block, 0, stream>>>(x, offset, mask, weight,
                                                   xT, wprep, mOffs, mWts);
        dcn_ksplit<<<dim3(2048), block, 0, stream>>>(xT, mOffs, mWts, bias, wprep, out);
    } else {
        xpose_bf16<<<dim3(B_ * H_), block, 0, stream>>>(x, xT);
        prep_weight_fb<<<dim3(144), block, 0, stream>>>(weight, wprep);
        dcn_mfma_nhwc<<<dim3(B_ * H_ * 2), block, 0, stream>>>(xT, offset, mask, bias, wprep, out);
    }
}

// Round 10
// 37.547 us; speedup vs baseline: 1.8110x; 1.8110x over previous
//
#include <hip/hip_runtime.h>

#define B_    4
#define CIN_  64
#define H_    128
#define W_    128
#define COUT_ 64
#define HW    (H_*W_)
#define KPOS  576

typedef __attribute__((ext_vector_type(8))) short    bf16x8;
typedef __attribute__((ext_vector_type(4))) short    bf16x4;
typedef __attribute__((ext_vector_type(4))) float    f32x4;
typedef __attribute__((ext_vector_type(4))) _Float16 f16x4;
typedef __attribute__((ext_vector_type(8))) _Float16 f16x8;

static __device__ __forceinline__ unsigned short f2bf(float f) {
    union { float f; unsigned u; } a; a.f = f;
    unsigned r = a.u + 0x7fffu + ((a.u >> 16) & 1u);   // RNE
    return (unsigned short)(r >> 16);
}
static __device__ __forceinline__ float bfl(unsigned u) {
    union { unsigned x; float f; } a; a.x = u << 16; return a.f;
}

#define XT_HALFS   4194304                       // B*HW*64 NHWC f16 image
#define WP_HALFS   36864                         // wt[k][co][c] f16
#define META_CNT   (B_*9*HW)                     // 589824
#define OFFS_BYTE  ((XT_HALFS + WP_HALFS) * 2)            // 8462336
#define WTS_BYTE   (OFFS_BYTE + META_CNT * 4)             // 10821632
#define WS_NEED3   ((size_t)(WTS_BYTE + META_CNT * 8))    // ~15.5 MB

// ================= fused prep: xpose | meta | weight (all f16) =============
__global__ __launch_bounds__(256)
void prep_all(const float* __restrict__ x,
              const float* __restrict__ offset,
              const float* __restrict__ mask,
              const float* __restrict__ w,
              _Float16* __restrict__ xT,
              _Float16* __restrict__ wt,
              unsigned* __restrict__ mOffs,
              f16x4* __restrict__ mWts)
{
    const int bid = blockIdx.x;
    const int t   = threadIdx.x;

    if (bid < 512) {
        // ---- x NCHW f32 -> NHWC f16 (one (b,y) row per block) ----
        __shared__ _Float16 ld[64 * 132];
        const int b = bid >> 7;
        const int y = bid & 127;
        const float* src = x + (size_t)b * 64 * HW + y * W_;
        #pragma unroll
        for (int i = 0; i < 8; ++i) {
            const int e4 = (t + i * 256) * 4;
            const int c  = e4 >> 7;
            const int x0 = e4 & 127;
            const float4 v = *(const float4*)(src + (size_t)c * HW + x0);
            _Float16* d = &ld[c * 132 + x0];
            d[0] = (_Float16)v.x; d[1] = (_Float16)v.y;
            d[2] = (_Float16)v.z; d[3] = (_Float16)v.w;
        }
        __syncthreads();
        _Float16* dst = xT + ((size_t)b * HW + (size_t)y * W_) * 64;
        #pragma unroll
        for (int i = 0; i < 4; ++i) {
            const int o    = (t + i * 256) * 8;
            const int xcol = o >> 6;
            const int c0   = o & 63;
            union { f16x8 v; _Float16 u[8]; } pk;
            #pragma unroll
            for (int j = 0; j < 8; ++j) pk.u[j] = ld[(c0 + j) * 132 + xcol];
            *(f16x8*)(dst + o) = pk.v;
        }
    } else if (bid < 2816) {
        // ---- sampling metadata per (b,tap,pixel) ----
        const int i  = (bid - 512) * 256 + t;
        const int gp = i & (HW - 1);
        const int bk = i >> 14;              // b*9 + k
        const int b  = bk / 9;
        const int k  = bk - b * 9;
        const int ho = gp >> 7, wo = gp & 127;
        const float dy = offset[(size_t)(b * 18 + 2 * k) * HW + gp];
        const float dx = offset[(size_t)(b * 18 + 2 * k + 1) * HW + gp];
        const float mm = mask[(size_t)bk * HW + gp];
        const float py  = dy + (float)(k / 3) + (float)(ho - 1);   // PAD=1
        const float pxx = dx + (float)(k % 3) + (float)(wo - 1);
        const float y0f = floorf(py), x0f = floorf(pxx);
        const float wy = py - y0f, wx = pxx - x0f;
        const int y0 = (int)y0f, x0 = (int)x0f;
        const int y1 = y0 + 1,  x1 = x0 + 1;
        const bool vy0 = (y0 >= 0) & (y0 < H_), vy1 = (y1 >= 0) & (y1 < H_);
        const bool vx0 = (x0 >= 0) & (x0 < W_), vx1 = (x1 >= 0) & (x1 < W_);
        const int cy0 = min(max(y0, 0), H_-1), cy1 = min(max(y1, 0), H_-1);
        const int cx0 = min(max(x0, 0), W_-1), cx1 = min(max(x1, 0), W_-1);
        mOffs[i] = (unsigned)cy0 | ((unsigned)cy1 << 8)
                 | ((unsigned)cx0 << 16) | ((unsigned)cx1 << 24);
        f16x4 wv;
        wv[0] = (_Float16)((vy0 && vx0) ? (1.f - wy) * (1.f - wx) * mm : 0.f);
        wv[1] = (_Float16)((vy0 && vx1) ? (1.f - wy) * wx * mm         : 0.f);
        wv[2] = (_Float16)((vy1 && vx0) ? wy * (1.f - wx) * mm         : 0.f);
        wv[3] = (_Float16)((vy1 && vx1) ? wy * wx * mm                 : 0.f);
        mWts[i] = wv;
    } else {
        // ---- weight -> f16, tap-major: wt[k][co][c] ----
        const int i = (bid - 2816) * 256 + t;
        if (i < 9 * 64 * 64) {
            const int k  = i >> 12;
            const int r  = i & 4095;
            const int co = r >> 6;
            const int c  = r & 63;
            wt[i] = (_Float16)w[co * KPOS + c * 9 + k];
        }
    }
}

// ================= main: R5 structure, f16 packed-math combine =============
// One block = 64 px x 64 cout. Wave layout for gather: pxl = lane>>2,
// coct = lane&3, 2 ch passes. LDS double-buffered, 1 barrier/tap.
// Combine: f16x8 vector fma (v_pk_fma_f16) -> result IS the f16 MFMA A-frag.
__global__ __launch_bounds__(256, 4)
void dcn_f16(const _Float16* __restrict__ xT,
             const unsigned* __restrict__ mOffs,
             const f16x4* __restrict__ mWts,
             const float* __restrict__ bias,
             const _Float16* __restrict__ wprep,
             float* __restrict__ out)
{
    __shared__ _Float16 vP[2][64][72];
    __shared__ _Float16 Wk[2][64][72];

    const int t   = threadIdx.x;
    const int bid = blockIdx.x;
    const int wk  = ((bid & 7) << 7) | (bid >> 3);   // XCD-chunked swizzle
    const int xh  = wk & 1;
    const int ho  = (wk >> 1) & 127;
    const int b   = wk >> 8;
    const int cq  = t >> 6;
    const int lane = t & 63;
    const int pxl  = lane >> 2;          // 0..15 pixel within wave tile
    const int coct = lane & 3;           // 0..3 channel oct

    f32x4 acc[4];
    #pragma unroll
    for (int i = 0; i < 4; ++i) acc[i] = (f32x4){0.f, 0.f, 0.f, 0.f};

    const _Float16* xTb = xT + (size_t)b * HW * 64;
    const int gp    = ho * W_ + xh * 64 + cq * 16 + pxl;
    const int mbase = (b * 9) << 14;

    // ---- all 9 taps' metadata up front ----
    unsigned pk9[9]; f16x4 wh9[9];
    #pragma unroll
    for (int k = 0; k < 9; ++k) {
        const int mi = mbase + (k << 14) + gp;
        pk9[k] = mOffs[mi];
        wh9[k] = mWts[mi];
    }

    f16x8 cr[2][4];   // [pass][corner] in-flight gather regs

    auto ld = [&](int k) {
        const unsigned pk = pk9[k];
        const int y0c = pk & 255,         y1c = (pk >> 8) & 255;
        const int x0c = (pk >> 16) & 255, x1c = (int)(pk >> 24);
        const int cho = coct * 8;
        const int p00 = (((y0c << 7) | x0c) << 6) + cho;
        const int p01 = (((y0c << 7) | x1c) << 6) + cho;
        const int p10 = (((y1c << 7) | x0c) << 6) + cho;
        const int p11 = (((y1c << 7) | x1c) << 6) + cho;
        #pragma unroll
        for (int pass = 0; pass < 2; ++pass) {
            const int o = pass * 32;
            cr[pass][0] = *(const f16x8*)(xTb + p00 + o);
            cr[pass][1] = *(const f16x8*)(xTb + p01 + o);
            cr[pass][2] = *(const f16x8*)(xTb + p10 + o);
            cr[pass][3] = *(const f16x8*)(xTb + p11 + o);
        }
    };

    auto fin = [&](int k) {
        const int s = k & 1;
        // stage Wk tap k (2 x b128 per thread, coalesced)
        {
            const int j  = t * 8;
            *(f16x8*)&Wk[s][j >> 6][j & 63] =
                *(const f16x8*)(wprep + k * 4096 + j);
            const int j2 = 2048 + j;
            *(f16x8*)&Wk[s][j2 >> 6][j2 & 63] =
                *(const f16x8*)(wprep + k * 4096 + j2);
        }
        const _Float16 w0 = wh9[k][0];
        const _Float16 w1 = wh9[k][1];
        const _Float16 w2 = wh9[k][2];
        const _Float16 w3 = wh9[k][3];
        #pragma unroll
        for (int pass = 0; pass < 2; ++pass) {
            // packed-f16 bilinear combine: result IS the A-fragment slice
            f16x8 a = cr[pass][0] * w0 + cr[pass][1] * w1
                    + cr[pass][2] * w2 + cr[pass][3] * w3;
            *(f16x8*)&vP[s][cq * 16 + pxl][pass * 32 + coct * 8] = a;
        }
    };

    auto domfma = [&](int k) {
        const int s  = k & 1;
        const int ra = cq * 16 + (lane & 15);
        const int kc = (lane >> 4) * 8;
        #pragma unroll
        for (int ks = 0; ks < 2; ++ks) {
            const int kcol = ks * 32 + kc;
            const f16x8 a = *(const f16x8*)&vP[s][ra][kcol];
            #pragma unroll
            for (int nt = 0; nt < 4; ++nt) {
                const f16x8 bb = *(const f16x8*)&Wk[s][nt * 16 + (lane & 15)][kcol];
                acc[nt] = __builtin_amdgcn_mfma_f32_16x16x32_f16(a, bb, acc[nt], 0, 0, 0);
            }
        }
    };

    ld(0);
    fin(0);
    __syncthreads();
    #pragma unroll
    for (int k = 0; k < 9; ++k) {
        if (k < 8) ld(k + 1);     // issue next tap's gather
        domfma(k);                // consume LDS tap k
        if (k < 8) fin(k + 1);    // wait loads, combine, write LDS
        __syncthreads();
    }

    const int px0 = cq * 16 + (lane >> 4) * 4;
    #pragma unroll
    for (int nt = 0; nt < 4; ++nt) {
        const int co = nt * 16 + (lane & 15);
        const float bb = bias[co];
        float4 r;
        r.x = acc[nt][0] + bb;
        r.y = acc[nt][1] + bb;
        r.z = acc[nt][2] + bb;
        r.w = acc[nt][3] + bb;
        *(float4*)&out[(((size_t)b * COUT_ + co) * H_ + ho) * W_ + xh * 64 + px0] = r;
    }
}

// ================= fallback path (ws too small): R4 bf16 kernels ===========
__global__ __launch_bounds__(256)
void xpose_bf16(const float* __restrict__ x, unsigned short* __restrict__ xT)
{
    __shared__ unsigned short ld[64 * 132];
    const int t   = threadIdx.x;
    const int blk = blockIdx.x;
    const int b   = blk >> 7;
    const int y   = blk & 127;
    const float* src = x + (size_t)b * 64 * HW + y * W_;
    #pragma unroll
    for (int i = 0; i < 8; ++i) {
        const int e4 = (t + i * 256) * 4;
        const int c  = e4 >> 7;
        const int x0 = e4 & 127;
        const float4 v = *(const float4*)(src + (size_t)c * HW + x0);
        unsigned short* d = &ld[c * 132 + x0];
        d[0] = f2bf(v.x); d[1] = f2bf(v.y); d[2] = f2bf(v.z); d[3] = f2bf(v.w);
    }
    __syncthreads();
    unsigned short* dst = xT + ((size_t)b * HW + (size_t)y * W_) * 64;
    #pragma unroll
    for (int i = 0; i < 4; ++i) {
        const int o    = (t + i * 256) * 8;
        const int xcol = o >> 6;
        const int c0   = o & 63;
        union { bf16x8 v; unsigned short u[8]; } pk;
        #pragma unroll
        for (int j = 0; j < 8; ++j) pk.u[j] = ld[(c0 + j) * 132 + xcol];
        *(bf16x8*)(dst + o) = pk.v;
    }
}

__global__ void prep_weight_fb(const float* __restrict__ w,
                               unsigned short* __restrict__ wt)
{
    const int i = blockIdx.x * 256 + threadIdx.x;
    if (i >= 9 * 64 * 64) return;
    const int k  = i >> 12;
    const int r  = i & 4095;
    const int co = r >> 6;
    const int c  = r & 63;
    wt[i] = f2bf(w[co * KPOS + c * 9 + k]);
}

__global__ __launch_bounds__(256, 4)
void dcn_mfma_nhwc(const unsigned short* __restrict__ xT,
                   const float* __restrict__ offset,
                   const float* __restrict__ mask,
                   const float* __restrict__ bias,
                   const unsigned short* __restrict__ wprep,
                   float* __restrict__ out)
{
    __shared__ unsigned short vP[2][64][72];
    __shared__ unsigned short Wk[2][64][72];
    const int t   = threadIdx.x;
    const int bid = blockIdx.x;
    const int wk  = ((bid & 7) << 7) | (bid >> 3);
    const int xh  = wk & 1;
    const int ho  = (wk >> 1) & 127;
    const int b   = wk >> 8;
    const int cq  = t >> 6;
    const int lane = t & 63;
    const int px_sub = lane >> 4;
    const int c4     = lane & 15;
    f32x4 acc[4];
    #pragma unroll
    for (int i = 0; i < 4; ++i) acc[i] = (f32x4){0.f, 0.f, 0.f, 0.f};
    const unsigned short* xTb = xT + (size_t)b * HW * 64;

    auto stage = [&](int k, int s) {
        int   idxs[4][4];
        float wts [4][4];
        #pragma unroll
        for (int it = 0; it < 4; ++it) {
            const int pl = (cq << 4) | (it << 2) | px_sub;
            const int wo = xh * 64 + pl;
            const int obase = ((b * 18 + 2 * k) * H_ + ho) * W_ + wo;
            const float dy = offset[obase];
            const float dx = offset[obase + HW];
            const float mm = mask[((b * 9 + k) * H_ + ho) * W_ + wo];
            const float py  = dy + (float)(k / 3) + (float)(ho - 1);
            const float pxx = dx + (float)(k % 3) + (float)(wo - 1);
            const float y0f = floorf(py), x0f = floorf(pxx);
            const float wy = py - y0f, wx = pxx - x0f;
            const int y0 = (int)y0f, x0 = (int)x0f;
            const int y1 = y0 + 1,  x1 = x0 + 1;
            const bool vy0 = (y0 >= 0) & (y0 < H_), vy1 = (y1 >= 0) & (y1 < H_);
            const bool vx0 = (x0 >= 0) & (x0 < W_), vx1 = (x1 >= 0) & (x1 < W_);
            const int cy0 = min(max(y0, 0), H_-1), cy1 = min(max(y1, 0), H_-1);
            const int cx0 = min(max(x0, 0), W_-1), cx1 = min(max(x1, 0), W_-1);
            idxs[it][0] = (cy0 * W_ + cx0) << 6;
            idxs[it][1] = (cy0 * W_ + cx1) << 6;
            idxs[it][2] = (cy1 * W_ + cx0) << 6;
            idxs[it][3] = (cy1 * W_ + cx1) << 6;
            wts[it][0] = (vy0 && vx0) ? (1.f - wy) * (1.f - wx) * mm : 0.f;
            wts[it][1] = (vy0 && vx1) ? (1.f - wy) * wx * mm         : 0.f;
            wts[it][2] = (vy1 && vx0) ? wy * (1.f - wx) * mm         : 0.f;
            wts[it][3] = (vy1 && vx1) ? wy * wx * mm                 : 0.f;
        }
        bf16x4 cr[4][4];
        #pragma unroll
        for (int it = 0; it < 4; ++it)
            #pragma unroll
            for (int cn = 0; cn < 4; ++cn)
                cr[it][cn] = *(const bf16x4*)(xTb + idxs[it][cn] + (c4 << 2));
        #pragma unroll
        for (int q = 0; q < 2; ++q) {
            const int j  = q * 2048 + t * 8;
            *(bf16x8*)&Wk[s][j >> 6][j & 63] = *(const bf16x8*)(wprep + k * 4096 + j);
        }
        #pragma unroll
        for (int it = 0; it < 4; ++it) {
            const int pl = (cq << 4) | (it << 2) | px_sub;
            union { bf16x4 v; unsigned short u[4]; } pk;
            #pragma unroll
            for (int j = 0; j < 4; ++j) {
                union { short s; unsigned short u; } s0{cr[it][0][j]}, s1{cr[it][1][j]},
                                                     s2{cr[it][2][j]}, s3{cr[it][3][j]};
                const float v = wts[it][0] * bfl(s0.u) + wts[it][1] * bfl(s1.u)
                              + wts[it][2] * bfl(s2.u) + wts[it][3] * bfl(s3.u);
                pk.u[j] = f2bf(v);
            }
            *(bf16x4*)&vP[s][pl][c4 << 2] = pk.v;
        }
    };
    auto domfma = [&](int s) {
        const int ra = cq * 16 + (lane & 15);
        const int kc = (lane >> 4) * 8;
        #pragma unroll
        for (int ks = 0; ks < 2; ++ks) {
            const int kcol = ks * 32 + kc;
            const bf16x8 a = *(const bf16x8*)&vP[s][ra][kcol];
            #pragma unroll
            for (int nt = 0; nt < 4; ++nt) {
                const bf16x8 bb = *(const bf16x8*)&Wk[s][nt * 16 + (lane & 15)][kcol];
                acc[nt] = __builtin_amdgcn_mfma_f32_16x16x32_bf16(a, bb, acc[nt], 0, 0, 0);
            }
        }
    };
    stage(0, 0);
    __syncthreads();
    for (int k = 0; k < 9; ++k) {
        const int s = k & 1;
        if (k < 8) stage(k + 1, s ^ 1);
        domfma(s);
        __syncthreads();
    }
    const int px0 = cq * 16 + (lane >> 4) * 4;
    #pragma unroll
    for (int nt = 0; nt < 4; ++nt) {
        const int co = nt * 16 + (lane & 15);
        const float bb = bias[co];
        float4 r;
        r.x = acc[nt][0] + bb;
        r.y = acc[nt][1] + bb;
        r.z = acc[nt][2] + bb;
        r.w = acc[nt][3] + bb;
        *(float4*)&out[(((size_t)b * COUT_ + co) * H_ + ho) * W_ + xh * 64 + px0] = r;
    }
}

extern "C" void kernel_launch(void* const* d_in, const int* in_sizes, int n_in,
                              void* d_out, int out_size, void* d_ws, size_t ws_size,
                              hipStream_t stream)
{
    const float* x      = (const float*)d_in[0];
    const float* offset = (const float*)d_in[1];
    const float* mask   = (const float*)d_in[2];
    const float* weight = (const float*)d_in[3];
    const float* bias   = (const float*)d_in[4];
    float* out = (float*)d_out;

    dim3 block(256);
    dim3 grid(B_ * H_ * 2);

    if (ws_size >= WS_NEED3) {
        _Float16* xT    = (_Float16*)d_ws;
        _Float16* wprep = xT + XT_HALFS;
        unsigned* mOffs = (unsigned*)((char*)d_ws + OFFS_BYTE);
        f16x4*    mWts  = (f16x4*)  ((char*)d_ws + WTS_BYTE);
        prep_all<<<dim3(2960), block, 0, stream>>>(x, offset, mask, weight,
                                                   xT, wprep, mOffs, mWts);
        dcn_f16<<<grid, block, 0, stream>>>(xT, mOffs, mWts, bias, wprep, out);
    } else {
        unsigned short* xTb   = (unsigned short*)d_ws;
        unsigned short* wprep = xTb + XT_HALFS;
        xpose_bf16<<<dim3(B_ * H_), block, 0, stream>>>(x, xTb);
        prep_weight_fb<<<dim3(144), block, 0, stream>>>(weight, wprep);
        dcn_mfma_nhwc<<<grid, block, 0, stream>>>(xTb, offset, mask, bias, wprep, out);
    }
}

// Round 11
// 35.146 us; speedup vs baseline: 1.9347x; 1.0683x over previous
//
#include <hip/hip_runtime.h>

#define B_    4
#define CIN_  64
#define H_    128
#define W_    128
#define COUT_ 64
#define HW    (H_*W_)
#define KPOS  576

typedef __attribute__((ext_vector_type(8))) short    bf16x8;
typedef __attribute__((ext_vector_type(4))) short    bf16x4;
typedef __attribute__((ext_vector_type(4))) float    f32x4;
typedef __attribute__((ext_vector_type(4))) _Float16 f16x4;
typedef __attribute__((ext_vector_type(8))) _Float16 f16x8;

static __device__ __forceinline__ unsigned short f2bf(float f) {
    union { float f; unsigned u; } a; a.f = f;
    unsigned r = a.u + 0x7fffu + ((a.u >> 16) & 1u);   // RNE
    return (unsigned short)(r >> 16);
}
static __device__ __forceinline__ float bfl(unsigned u) {
    union { unsigned x; float f; } a; a.x = u << 16; return a.f;
}

#define XT_HALFS   4194304                       // B*HW*64 NHWC f16 image
#define WP_HALFS   36864                         // wt[k][co][c] f16
#define META_CNT   (B_*9*HW)                     // 589824
#define OFFS_BYTE  ((XT_HALFS + WP_HALFS) * 2)            // 8462336
#define WTS_BYTE   (OFFS_BYTE + META_CNT * 4)             // 10821632
#define WS_NEED3   ((size_t)(WTS_BYTE + META_CNT * 8))    // ~15.5 MB

// ================= fused prep: xpose | meta | weight (all f16) =============
__global__ __launch_bounds__(256)
void prep_all(const float* __restrict__ x,
              const float* __restrict__ offset,
              const float* __restrict__ mask,
              const float* __restrict__ w,
              _Float16* __restrict__ xT,
              _Float16* __restrict__ wt,
              unsigned* __restrict__ mOffs,
              f16x4* __restrict__ mWts)
{
    const int bid = blockIdx.x;
    const int t   = threadIdx.x;

    if (bid < 512) {
        // ---- x NCHW f32 -> NHWC f16 (one (b,y) row per block) ----
        __shared__ _Float16 ld[64 * 132];
        const int b = bid >> 7;
        const int y = bid & 127;
        const float* src = x + (size_t)b * 64 * HW + y * W_;
        #pragma unroll
        for (int i = 0; i < 8; ++i) {
            const int e4 = (t + i * 256) * 4;
            const int c  = e4 >> 7;
            const int x0 = e4 & 127;
            const float4 v = *(const float4*)(src + (size_t)c * HW + x0);
            _Float16* d = &ld[c * 132 + x0];
            d[0] = (_Float16)v.x; d[1] = (_Float16)v.y;
            d[2] = (_Float16)v.z; d[3] = (_Float16)v.w;
        }
        __syncthreads();
        _Float16* dst = xT + ((size_t)b * HW + (size_t)y * W_) * 64;
        #pragma unroll
        for (int i = 0; i < 4; ++i) {
            const int o    = (t + i * 256) * 8;
            const int xcol = o >> 6;
            const int c0   = o & 63;
            union { f16x8 v; _Float16 u[8]; } pk;
            #pragma unroll
            for (int j = 0; j < 8; ++j) pk.u[j] = ld[(c0 + j) * 132 + xcol];
            *(f16x8*)(dst + o) = pk.v;
        }
    } else if (bid < 2816) {
        // ---- sampling metadata per (b,tap,pixel) ----
        const int i  = (bid - 512) * 256 + t;
        const int gp = i & (HW - 1);
        const int bk = i >> 14;              // b*9 + k
        const int b  = bk / 9;
        const int k  = bk - b * 9;
        const int ho = gp >> 7, wo = gp & 127;
        const float dy = offset[(size_t)(b * 18 + 2 * k) * HW + gp];
        const float dx = offset[(size_t)(b * 18 + 2 * k + 1) * HW + gp];
        const float mm = mask[(size_t)bk * HW + gp];
        const float py  = dy + (float)(k / 3) + (float)(ho - 1);   // PAD=1
        const float pxx = dx + (float)(k % 3) + (float)(wo - 1);
        const float y0f = floorf(py), x0f = floorf(pxx);
        const float wy = py - y0f, wx = pxx - x0f;
        const int y0 = (int)y0f, x0 = (int)x0f;
        const int y1 = y0 + 1,  x1 = x0 + 1;
        const bool vy0 = (y0 >= 0) & (y0 < H_), vy1 = (y1 >= 0) & (y1 < H_);
        const bool vx0 = (x0 >= 0) & (x0 < W_), vx1 = (x1 >= 0) & (x1 < W_);
        const int cy0 = min(max(y0, 0), H_-1), cy1 = min(max(y1, 0), H_-1);
        const int cx0 = min(max(x0, 0), W_-1), cx1 = min(max(x1, 0), W_-1);
        mOffs[i] = (unsigned)cy0 | ((unsigned)cy1 << 8)
                 | ((unsigned)cx0 << 16) | ((unsigned)cx1 << 24);
        f16x4 wv;
        wv[0] = (_Float16)((vy0 && vx0) ? (1.f - wy) * (1.f - wx) * mm : 0.f);
        wv[1] = (_Float16)((vy0 && vx1) ? (1.f - wy) * wx * mm         : 0.f);
        wv[2] = (_Float16)((vy1 && vx0) ? wy * (1.f - wx) * mm         : 0.f);
        wv[3] = (_Float16)((vy1 && vx1) ? wy * wx * mm                 : 0.f);
        mWts[i] = wv;
    } else {
        // ---- weight -> f16, tap-major: wt[k][co][c] ----
        const int i = (bid - 2816) * 256 + t;
        if (i < 9 * 64 * 64) {
            const int k  = i >> 12;
            const int r  = i & 4095;
            const int co = r >> 6;
            const int c  = r & 63;
            wt[i] = (_Float16)w[co * KPOS + c * 9 + k];
        }
    }
}

// ================= main: R10 structure + 2-tap-deep gather prefetch ========
// Per iter k: wkload(k+1)->regs | metald(k+2) | domfma(k) | gather(k+2) |
// finish(k+1) {Wk LDS write + combine + vP write} | barrier.
// Gathers get ~1.5 iterations (>1500 cyc) of latency cover.
__global__ __launch_bounds__(256, 4)
void dcn_f16(const _Float16* __restrict__ xT,
             const unsigned* __restrict__ mOffs,
             const f16x4* __restrict__ mWts,
             const float* __restrict__ bias,
             const _Float16* __restrict__ wprep,
             float* __restrict__ out)
{
    __shared__ _Float16 vP[2][64][72];
    __shared__ _Float16 Wk[2][64][72];

    const int t   = threadIdx.x;
    const int bid = blockIdx.x;
    const int wk  = ((bid & 7) << 7) | (bid >> 3);   // XCD-chunked swizzle
    const int xh  = wk & 1;
    const int ho  = (wk >> 1) & 127;
    const int b   = wk >> 8;
    const int cq  = t >> 6;
    const int lane = t & 63;
    const int pxl  = lane >> 2;          // 0..15 pixel within wave tile
    const int coct = lane & 3;           // 0..3 channel oct

    f32x4 acc[4];
    #pragma unroll
    for (int i = 0; i < 4; ++i) acc[i] = (f32x4){0.f, 0.f, 0.f, 0.f};

    const _Float16* xTb = xT + (size_t)b * HW * 64;
    const int gp    = ho * W_ + xh * 64 + cq * 16 + pxl;
    const int mbase = (b * 9) << 14;

    // rolling pipeline state (static indices under full unroll)
    unsigned mO[2]; f16x4 mW[2];
    f16x8 cr[2][2][4];                   // [tap parity][pass][corner]
    f16x8 wa0, wa1;                      // W-stage registers (T14 split)

    auto metald = [&](int k, int s) {
        const int mi = mbase + (k << 14) + gp;
        mO[s] = mOffs[mi];
        mW[s] = mWts[mi];
    };
    auto gather = [&](int k, int s) {
        const unsigned pk = mO[s];
        const int y0c = pk & 255,         y1c = (pk >> 8) & 255;
        const int x0c = (pk >> 16) & 255, x1c = (int)(pk >> 24);
        const int cho = coct * 8;
        const int p00 = (((y0c << 7) | x0c) << 6) + cho;
        const int p01 = (((y0c << 7) | x1c) << 6) + cho;
        const int p10 = (((y1c << 7) | x0c) << 6) + cho;
        const int p11 = (((y1c << 7) | x1c) << 6) + cho;
        #pragma unroll
        for (int pass = 0; pass < 2; ++pass) {
            const int o = pass * 32;
            cr[s][pass][0] = *(const f16x8*)(xTb + p00 + o);
            cr[s][pass][1] = *(const f16x8*)(xTb + p01 + o);
            cr[s][pass][2] = *(const f16x8*)(xTb + p10 + o);
            cr[s][pass][3] = *(const f16x8*)(xTb + p11 + o);
        }
    };
    auto wkload = [&](int k) {
        const int j = t * 8;
        wa0 = *(const f16x8*)(wprep + k * 4096 + j);
        wa1 = *(const f16x8*)(wprep + k * 4096 + 2048 + j);
    };
    auto finish = [&](int k, int s) {
        // write staged W regs to LDS
        const int j  = t * 8;
        *(f16x8*)&Wk[s][j >> 6][j & 63] = wa0;
        const int j2 = 2048 + j;
        *(f16x8*)&Wk[s][j2 >> 6][j2 & 63] = wa1;
        // packed-f16 bilinear combine -> A-fragment slice, write vP
        const _Float16 w0 = mW[s][0];
        const _Float16 w1 = mW[s][1];
        const _Float16 w2 = mW[s][2];
        const _Float16 w3 = mW[s][3];
        #pragma unroll
        for (int pass = 0; pass < 2; ++pass) {
            f16x8 a = cr[s][pass][0] * w0 + cr[s][pass][1] * w1
                    + cr[s][pass][2] * w2 + cr[s][pass][3] * w3;
            *(f16x8*)&vP[s][cq * 16 + pxl][pass * 32 + coct * 8] = a;
        }
    };
    auto domfma = [&](int k) {
        const int s  = k & 1;
        const int ra = cq * 16 + (lane & 15);
        const int kc = (lane >> 4) * 8;
        #pragma unroll
        for (int ks = 0; ks < 2; ++ks) {
            const int kcol = ks * 32 + kc;
            const f16x8 a = *(const f16x8*)&vP[s][ra][kcol];
            #pragma unroll
            for (int nt = 0; nt < 4; ++nt) {
                const f16x8 bb = *(const f16x8*)&Wk[s][nt * 16 + (lane & 15)][kcol];
                acc[nt] = __builtin_amdgcn_mfma_f32_16x16x32_f16(a, bb, acc[nt], 0, 0, 0);
            }
        }
    };

    // ---- prologue: taps 0 and 1 in flight, tap 0 finished ----
    metald(0, 0);
    metald(1, 1);
    gather(0, 0);
    gather(1, 1);
    wkload(0);
    finish(0, 0);
    __syncthreads();

    #pragma unroll
    for (int k = 0; k < 9; ++k) {
        const int s = k & 1;
        if (k < 8) wkload(k + 1);        // next tap's W into regs (L1-hot)
        if (k < 7) metald(k + 2, s);     // meta 2 ahead (slot s free now)
        domfma(k);                       // compute; covers meta/W latency
        if (k < 7) gather(k + 2, s);     // gathers issued 2 taps ahead
        if (k < 8) {
            finish(k + 1, s ^ 1);        // wait cr[(k+1)&1] (1.5 iters old)
            __syncthreads();
        }
    }

    // ---- epilogue: D col = lane&15 (co), row = (lane>>4)*4+j (pixel) ----
    const int px0 = cq * 16 + (lane >> 4) * 4;
    #pragma unroll
    for (int nt = 0; nt < 4; ++nt) {
        const int co = nt * 16 + (lane & 15);
        const float bb = bias[co];
        float4 r;
        r.x = acc[nt][0] + bb;
        r.y = acc[nt][1] + bb;
        r.z = acc[nt][2] + bb;
        r.w = acc[nt][3] + bb;
        *(float4*)&out[(((size_t)b * COUT_ + co) * H_ + ho) * W_ + xh * 64 + px0] = r;
    }
}

// ================= fallback path (ws too small): R4 bf16 kernels ===========
__global__ __launch_bounds__(256)
void xpose_bf16(const float* __restrict__ x, unsigned short* __restrict__ xT)
{
    __shared__ unsigned short ld[64 * 132];
    const int t   = threadIdx.x;
    const int blk = blockIdx.x;
    const int b   = blk >> 7;
    const int y   = blk & 127;
    const float* src = x + (size_t)b * 64 * HW + y * W_;
    #pragma unroll
    for (int i = 0; i < 8; ++i) {
        const int e4 = (t + i * 256) * 4;
        const int c  = e4 >> 7;
        const int x0 = e4 & 127;
        const float4 v = *(const float4*)(src + (size_t)c * HW + x0);
        unsigned short* d = &ld[c * 132 + x0];
        d[0] = f2bf(v.x); d[1] = f2bf(v.y); d[2] = f2bf(v.z); d[3] = f2bf(v.w);
    }
    __syncthreads();
    unsigned short* dst = xT + ((size_t)b * HW + (size_t)y * W_) * 64;
    #pragma unroll
    for (int i = 0; i < 4; ++i) {
        const int o    = (t + i * 256) * 8;
        const int xcol = o >> 6;
        const int c0   = o & 63;
        union { bf16x8 v; unsigned short u[8]; } pk;
        #pragma unroll
        for (int j = 0; j < 8; ++j) pk.u[j] = ld[(c0 + j) * 132 + xcol];
        *(bf16x8*)(dst + o) = pk.v;
    }
}

__global__ void prep_weight_fb(const float* __restrict__ w,
                               unsigned short* __restrict__ wt)
{
    const int i = blockIdx.x * 256 + threadIdx.x;
    if (i >= 9 * 64 * 64) return;
    const int k  = i >> 12;
    const int r  = i & 4095;
    const int co = r >> 6;
    const int c  = r & 63;
    wt[i] = f2bf(w[co * KPOS + c * 9 + k]);
}

__global__ __launch_bounds__(256, 4)
void dcn_mfma_nhwc(const unsigned short* __restrict__ xT,
                   const float* __restrict__ offset,
                   const float* __restrict__ mask,
                   const float* __restrict__ bias,
                   const unsigned short* __restrict__ wprep,
                   float* __restrict__ out)
{
    __shared__ unsigned short vP[2][64][72];
    __shared__ unsigned short Wk[2][64][72];
    const int t   = threadIdx.x;
    const int bid = blockIdx.x;
    const int wk  = ((bid & 7) << 7) | (bid >> 3);
    const int xh  = wk & 1;
    const int ho  = (wk >> 1) & 127;
    const int b   = wk >> 8;
    const int cq  = t >> 6;
    const int lane = t & 63;
    const int px_sub = lane >> 4;
    const int c4     = lane & 15;
    f32x4 acc[4];
    #pragma unroll
    for (int i = 0; i < 4; ++i) acc[i] = (f32x4){0.f, 0.f, 0.f, 0.f};
    const unsigned short* xTb = xT + (size_t)b * HW * 64;

    auto stage = [&](int k, int s) {
        int   idxs[4][4];
        float wts [4][4];
        #pragma unroll
        for (int it = 0; it < 4; ++it) {
            const int pl = (cq << 4) | (it << 2) | px_sub;
            const int wo = xh * 64 + pl;
            const int obase = ((b * 18 + 2 * k) * H_ + ho) * W_ + wo;
            const float dy = offset[obase];
            const float dx = offset[obase + HW];
            const float mm = mask[((b * 9 + k) * H_ + ho) * W_ + wo];
            const float py  = dy + (float)(k / 3) + (float)(ho - 1);
            const float pxx = dx + (float)(k % 3) + (float)(wo - 1);
            const float y0f = floorf(py), x0f = floorf(pxx);
            const float wy = py - y0f, wx = pxx - x0f;
            const int y0 = (int)y0f, x0 = (int)x0f;
            const int y1 = y0 + 1,  x1 = x0 + 1;
            const bool vy0 = (y0 >= 0) & (y0 < H_), vy1 = (y1 >= 0) & (y1 < H_);
            const bool vx0 = (x0 >= 0) & (x0 < W_), vx1 = (x1 >= 0) & (x1 < W_);
            const int cy0 = min(max(y0, 0), H_-1), cy1 = min(max(y1, 0), H_-1);
            const int cx0 = min(max(x0, 0), W_-1), cx1 = min(max(x1, 0), W_-1);
            idxs[it][0] = (cy0 * W_ + cx0) << 6;
            idxs[it][1] = (cy0 * W_ + cx1) << 6;
            idxs[it][2] = (cy1 * W_ + cx0) << 6;
            idxs[it][3] = (cy1 * W_ + cx1) << 6;
            wts[it][0] = (vy0 && vx0) ? (1.f - wy) * (1.f - wx) * mm : 0.f;
            wts[it][1] = (vy0 && vx1) ? (1.f - wy) * wx * mm         : 0.f;
            wts[it][2] = (vy1 && vx0) ? wy * (1.f - wx) * mm         : 0.f;
            wts[it][3] = (vy1 && vx1) ? wy * wx * mm                 : 0.f;
        }
        bf16x4 cr[4][4];
        #pragma unroll
        for (int it = 0; it < 4; ++it)
            #pragma unroll
            for (int cn = 0; cn < 4; ++cn)
                cr[it][cn] = *(const bf16x4*)(xTb + idxs[it][cn] + (c4 << 2));
        #pragma unroll
        for (int q = 0; q < 2; ++q) {
            const int j  = q * 2048 + t * 8;
            *(bf16x8*)&Wk[s][j >> 6][j & 63] = *(const bf16x8*)(wprep + k * 4096 + j);
        }
        #pragma unroll
        for (int it = 0; it < 4; ++it) {
            const int pl = (cq << 4) | (it << 2) | px_sub;
            union { bf16x4 v; unsigned short u[4]; } pk;
            #pragma unroll
            for (int j = 0; j < 4; ++j) {
                union { short s; unsigned short u; } s0{cr[it][0][j]}, s1{cr[it][1][j]},
                                                     s2{cr[it][2][j]}, s3{cr[it][3][j]};
                const float v = wts[it][0] * bfl(s0.u) + wts[it][1] * bfl(s1.u)
                              + wts[it][2] * bfl(s2.u) + wts[it][3] * bfl(s3.u);
                pk.u[j] = f2bf(v);
            }
            *(bf16x4*)&vP[s][pl][c4 << 2] = pk.v;
        }
    };
    auto domfma = [&](int s) {
        const int ra = cq * 16 + (lane & 15);
        const int kc = (lane >> 4) * 8;
        #pragma unroll
        for (int ks = 0; ks < 2; ++ks) {
            const int kcol = ks * 32 + kc;
            const bf16x8 a = *(const bf16x8*)&vP[s][ra][kcol];
            #pragma unroll
            for (int nt = 0; nt < 4; ++nt) {
                const bf16x8 bb = *(const bf16x8*)&Wk[s][nt * 16 + (lane & 15)][kcol];
                acc[nt] = __builtin_amdgcn_mfma_f32_16x16x32_bf16(a, bb, acc[nt], 0, 0, 0);
            }
        }
    };
    stage(0, 0);
    __syncthreads();
    for (int k = 0; k < 9; ++k) {
        const int s = k & 1;
        if (k < 8) stage(k + 1, s ^ 1);
        domfma(s);
        __syncthreads();
    }
    const int px0 = cq * 16 + (lane >> 4) * 4;
    #pragma unroll
    for (int nt = 0; nt < 4; ++nt) {
        const int co = nt * 16 + (lane & 15);
        const float bb = bias[co];
        float4 r;
        r.x = acc[nt][0] + bb;
        r.y = acc[nt][1] + bb;
        r.z = acc[nt][2] + bb;
        r.w = acc[nt][3] + bb;
        *(float4*)&out[(((size_t)b * COUT_ + co) * H_ + ho) * W_ + xh * 64 + px0] = r;
    }
}

extern "C" void kernel_launch(void* const* d_in, const int* in_sizes, int n_in,
                              void* d_out, int out_size, void* d_ws, size_t ws_size,
                              hipStream_t stream)
{
    const float* x      = (const float*)d_in[0];
    const float* offset = (const float*)d_in[1];
    const float* mask   = (const float*)d_in[2];
    const float* weight = (const float*)d_in[3];
    const float* bias   = (const float*)d_in[4];
    float* out = (float*)d_out;

    dim3 block(256);
    dim3 grid(B_ * H_ * 2);

    if (ws_size >= WS_NEED3) {
        _Float16* xT    = (_Float16*)d_ws;
        _Float16* wprep = xT + XT_HALFS;
        unsigned* mOffs = (unsigned*)((char*)d_ws + OFFS_BYTE);
        f16x4*    mWts  = (f16x4*)  ((char*)d_ws + WTS_BYTE);
        prep_all<<<dim3(2960), block, 0, stream>>>(x, offset, mask, weight,
                                                   xT, wprep, mOffs, mWts);
        dcn_f16<<<grid, block, 0, stream>>>(xT, mOffs, mWts, bias, wprep, out);
    } else {
        unsigned short* xTb   = (unsigned short*)d_ws;
        unsigned short* wprep = xTb + XT_HALFS;
        xpose_bf16<<<dim3(B_ * H_), block, 0, stream>>>(x, xTb);
        prep_weight_fb<<<dim3(144), block, 0, stream>>>(weight, wprep);
        dcn_mfma_nhwc<<<grid, block, 0, stream>>>(xTb, offset, mask, bias, wprep, out);
    }
}

// Round 12
// 34.876 us; speedup vs baseline: 1.9497x; 1.0077x over previous
//
#include <hip/hip_runtime.h>

#define B_    4
#define CIN_  64
#define H_    128
#define W_    128
#define COUT_ 64
#define HW    (H_*W_)
#define KPOS  576

typedef __attribute__((ext_vector_type(8))) short    bf16x8;
typedef __attribute__((ext_vector_type(4))) short    bf16x4;
typedef __attribute__((ext_vector_type(4))) float    f32x4;
typedef __attribute__((ext_vector_type(4))) _Float16 f16x4;
typedef __attribute__((ext_vector_type(8))) _Float16 f16x8;

static __device__ __forceinline__ unsigned short f2bf(float f) {
    union { float f; unsigned u; } a; a.f = f;
    unsigned r = a.u + 0x7fffu + ((a.u >> 16) & 1u);   // RNE
    return (unsigned short)(r >> 16);
}
static __device__ __forceinline__ float bfl(unsigned u) {
    union { unsigned x; float f; } a; a.x = u << 16; return a.f;
}

// Barrier that waits ONLY on LDS ops (lgkmcnt), never vmcnt: prefetched
// global loads stay in flight across taps (T4: counted waits, no drain-0).
// "memory" clobber pins LDS read/write motion across it (rule #18 family).
static __device__ __forceinline__ void softbar() {
    asm volatile("s_waitcnt lgkmcnt(0)\n\ts_barrier" ::: "memory");
}

#define XT_HALFS   4194304                       // B*HW*64 NHWC f16 image
#define WP_HALFS   36864                         // wt[k][co][c] f16
#define META_CNT   (B_*9*HW)                     // 589824
#define OFFS_BYTE  ((XT_HALFS + WP_HALFS) * 2)            // 8462336
#define WTS_BYTE   (OFFS_BYTE + META_CNT * 4)             // 10821632
#define WS_NEED3   ((size_t)(WTS_BYTE + META_CNT * 8))    // ~15.5 MB

// ================= fused prep: xpose | meta | weight (all f16) =============
__global__ __launch_bounds__(256)
void prep_all(const float* __restrict__ x,
              const float* __restrict__ offset,
              const float* __restrict__ mask,
              const float* __restrict__ w,
              _Float16* __restrict__ xT,
              _Float16* __restrict__ wt,
              unsigned* __restrict__ mOffs,
              f16x4* __restrict__ mWts)
{
    const int bid = blockIdx.x;
    const int t   = threadIdx.x;

    if (bid < 512) {
        // ---- x NCHW f32 -> NHWC f16 (one (b,y) row per block) ----
        __shared__ _Float16 ld[64 * 132];
        const int b = bid >> 7;
        const int y = bid & 127;
        const float* src = x + (size_t)b * 64 * HW + y * W_;
        #pragma unroll
        for (int i = 0; i < 8; ++i) {
            const int e4 = (t + i * 256) * 4;
            const int c  = e4 >> 7;
            const int x0 = e4 & 127;
            const float4 v = *(const float4*)(src + (size_t)c * HW + x0);
            _Float16* d = &ld[c * 132 + x0];
            d[0] = (_Float16)v.x; d[1] = (_Float16)v.y;
            d[2] = (_Float16)v.z; d[3] = (_Float16)v.w;
        }
        __syncthreads();
        _Float16* dst = xT + ((size_t)b * HW + (size_t)y * W_) * 64;
        #pragma unroll
        for (int i = 0; i < 4; ++i) {
            const int o    = (t + i * 256) * 8;
            const int xcol = o >> 6;
            const int c0   = o & 63;
            union { f16x8 v; _Float16 u[8]; } pk;
            #pragma unroll
            for (int j = 0; j < 8; ++j) pk.u[j] = ld[(c0 + j) * 132 + xcol];
            *(f16x8*)(dst + o) = pk.v;
        }
    } else if (bid < 2816) {
        // ---- sampling metadata per (b,tap,pixel) ----
        const int i  = (bid - 512) * 256 + t;
        const int gp = i & (HW - 1);
        const int bk = i >> 14;              // b*9 + k
        const int b  = bk / 9;
        const int k  = bk - b * 9;
        const int ho = gp >> 7, wo = gp & 127;
        const float dy = offset[(size_t)(b * 18 + 2 * k) * HW + gp];
        const float dx = offset[(size_t)(b * 18 + 2 * k + 1) * HW + gp];
        const float mm = mask[(size_t)bk * HW + gp];
        const float py  = dy + (float)(k / 3) + (float)(ho - 1);   // PAD=1
        const float pxx = dx + (float)(k % 3) + (float)(wo - 1);
        const float y0f = floorf(py), x0f = floorf(pxx);
        const float wy = py - y0f, wx = pxx - x0f;
        const int y0 = (int)y0f, x0 = (int)x0f;
        const int y1 = y0 + 1,  x1 = x0 + 1;
        const bool vy0 = (y0 >= 0) & (y0 < H_), vy1 = (y1 >= 0) & (y1 < H_);
        const bool vx0 = (x0 >= 0) & (x0 < W_), vx1 = (x1 >= 0) & (x1 < W_);
        const int cy0 = min(max(y0, 0), H_-1), cy1 = min(max(y1, 0), H_-1);
        const int cx0 = min(max(x0, 0), W_-1), cx1 = min(max(x1, 0), W_-1);
        mOffs[i] = (unsigned)cy0 | ((unsigned)cy1 << 8)
                 | ((unsigned)cx0 << 16) | ((unsigned)cx1 << 24);
        f16x4 wv;
        wv[0] = (_Float16)((vy0 && vx0) ? (1.f - wy) * (1.f - wx) * mm : 0.f);
        wv[1] = (_Float16)((vy0 && vx1) ? (1.f - wy) * wx * mm         : 0.f);
        wv[2] = (_Float16)((vy1 && vx0) ? wy * (1.f - wx) * mm         : 0.f);
        wv[3] = (_Float16)((vy1 && vx1) ? wy * wx * mm                 : 0.f);
        mWts[i] = wv;
    } else {
        // ---- weight -> f16, tap-major: wt[k][co][c] ----
        const int i = (bid - 2816) * 256 + t;
        if (i < 9 * 64 * 64) {
            const int k  = i >> 12;
            const int r  = i & 4095;
            const int co = r >> 6;
            const int c  = r & 63;
            wt[i] = (_Float16)w[co * KPOS + c * 9 + k];
        }
    }
}

// ================= main: R11 structure + lgkm-only barrier (no vmcnt drain)
// Per iter k: wkload(k+1)->regs | metald(k+2) | domfma(k) | gather(k+2) |
// finish(k+1) {Wk LDS write + combine + vP write} | softbar.
__global__ __launch_bounds__(256, 4)
void dcn_f16(const _Float16* __restrict__ xT,
             const unsigned* __restrict__ mOffs,
             const f16x4* __restrict__ mWts,
             const float* __restrict__ bias,
             const _Float16* __restrict__ wprep,
             float* __restrict__ out)
{
    __shared__ _Float16 vP[2][64][72];
    __shared__ _Float16 Wk[2][64][72];

    const int t   = threadIdx.x;
    const int bid = blockIdx.x;
    const int wk  = ((bid & 7) << 7) | (bid >> 3);   // XCD-chunked swizzle
    const int xh  = wk & 1;
    const int ho  = (wk >> 1) & 127;
    const int b   = wk >> 8;
    const int cq  = t >> 6;
    const int lane = t & 63;
    const int pxl  = lane >> 2;          // 0..15 pixel within wave tile
    const int coct = lane & 3;           // 0..3 channel oct

    f32x4 acc[4];
    #pragma unroll
    for (int i = 0; i < 4; ++i) acc[i] = (f32x4){0.f, 0.f, 0.f, 0.f};

    const _Float16* xTb = xT + (size_t)b * HW * 64;
    const int gp    = ho * W_ + xh * 64 + cq * 16 + pxl;
    const int mbase = (b * 9) << 14;

    // rolling pipeline state (static indices under full unroll)
    unsigned mO[2]; f16x4 mW[2];
    f16x8 cr[2][2][4];                   // [tap parity][pass][corner]
    f16x8 wa0, wa1;                      // W-stage registers (T14 split)

    auto metald = [&](int k, int s) {
        const int mi = mbase + (k << 14) + gp;
        mO[s] = mOffs[mi];
        mW[s] = mWts[mi];
    };
    auto gather = [&](int k, int s) {
        const unsigned pk = mO[s];
        const int y0c = pk & 255,         y1c = (pk >> 8) & 255;
        const int x0c = (pk >> 16) & 255, x1c = (int)(pk >> 24);
        const int cho = coct * 8;
        const int p00 = (((y0c << 7) | x0c) << 6) + cho;
        const int p01 = (((y0c << 7) | x1c) << 6) + cho;
        const int p10 = (((y1c << 7) | x0c) << 6) + cho;
        const int p11 = (((y1c << 7) | x1c) << 6) + cho;
        #pragma unroll
        for (int pass = 0; pass < 2; ++pass) {
            const int o = pass * 32;
            cr[s][pass][0] = *(const f16x8*)(xTb + p00 + o);
            cr[s][pass][1] = *(const f16x8*)(xTb + p01 + o);
            cr[s][pass][2] = *(const f16x8*)(xTb + p10 + o);
            cr[s][pass][3] = *(const f16x8*)(xTb + p11 + o);
        }
    };
    auto wkload = [&](int k) {
        const int j = t * 8;
        wa0 = *(const f16x8*)(wprep + k * 4096 + j);
        wa1 = *(const f16x8*)(wprep + k * 4096 + 2048 + j);
    };
    auto finish = [&](int k, int s) {
        // write staged W regs to LDS
        const int j  = t * 8;
        *(f16x8*)&Wk[s][j >> 6][j & 63] = wa0;
        const int j2 = 2048 + j;
        *(f16x8*)&Wk[s][j2 >> 6][j2 & 63] = wa1;
        // packed-f16 bilinear combine -> A-fragment slice, write vP
        const _Float16 w0 = mW[s][0];
        const _Float16 w1 = mW[s][1];
        const _Float16 w2 = mW[s][2];
        const _Float16 w3 = mW[s][3];
        #pragma unroll
        for (int pass = 0; pass < 2; ++pass) {
            f16x8 a = cr[s][pass][0] * w0 + cr[s][pass][1] * w1
                    + cr[s][pass][2] * w2 + cr[s][pass][3] * w3;
            *(f16x8*)&vP[s][cq * 16 + pxl][pass * 32 + coct * 8] = a;
        }
    };
    auto domfma = [&](int k) {
        const int s  = k & 1;
        const int ra = cq * 16 + (lane & 15);
        const int kc = (lane >> 4) * 8;
        #pragma unroll
        for (int ks = 0; ks < 2; ++ks) {
            const int kcol = ks * 32 + kc;
            const f16x8 a = *(const f16x8*)&vP[s][ra][kcol];
            #pragma unroll
            for (int nt = 0; nt < 4; ++nt) {
                const f16x8 bb = *(const f16x8*)&Wk[s][nt * 16 + (lane & 15)][kcol];
                acc[nt] = __builtin_amdgcn_mfma_f32_16x16x32_f16(a, bb, acc[nt], 0, 0, 0);
            }
        }
    };

    // ---- prologue: taps 0 and 1 in flight, tap 0 finished ----
    metald(0, 0);
    metald(1, 1);
    gather(0, 0);
    gather(1, 1);
    wkload(0);
    finish(0, 0);
    softbar();

    #pragma unroll
    for (int k = 0; k < 9; ++k) {
        const int s = k & 1;
        if (k < 8) wkload(k + 1);        // next tap's W into regs (L1-hot)
        if (k < 7) metald(k + 2, s);     // meta 2 ahead (slot s free now)
        domfma(k);                       // compute; covers meta/W latency
        if (k < 7) gather(k + 2, s);     // gathers issued 2 taps ahead
        if (k < 8) {
            finish(k + 1, s ^ 1);        // wait cr[(k+1)&1] (1.5 iters old)
            softbar();                   // lgkm-only: gathers stay in flight
        }
    }

    // ---- epilogue: D col = lane&15 (co), row = (lane>>4)*4+j (pixel) ----
    const int px0 = cq * 16 + (lane >> 4) * 4;
    #pragma unroll
    for (int nt = 0; nt < 4; ++nt) {
        const int co = nt * 16 + (lane & 15);
        const float bb = bias[co];
        float4 r;
        r.x = acc[nt][0] + bb;
        r.y = acc[nt][1] + bb;
        r.z = acc[nt][2] + bb;
        r.w = acc[nt][3] + bb;
        *(float4*)&out[(((size_t)b * COUT_ + co) * H_ + ho) * W_ + xh * 64 + px0] = r;
    }
}

// ================= fallback path (ws too small): R4 bf16 kernels ===========
__global__ __launch_bounds__(256)
void xpose_bf16(const float* __restrict__ x, unsigned short* __restrict__ xT)
{
    __shared__ unsigned short ld[64 * 132];
    const int t   = threadIdx.x;
    const int blk = blockIdx.x;
    const int b   = blk >> 7;
    const int y   = blk & 127;
    const float* src = x + (size_t)b * 64 * HW + y * W_;
    #pragma unroll
    for (int i = 0; i < 8; ++i) {
        const int e4 = (t + i * 256) * 4;
        const int c  = e4 >> 7;
        const int x0 = e4 & 127;
        const float4 v = *(const float4*)(src + (size_t)c * HW + x0);
        unsigned short* d = &ld[c * 132 + x0];
        d[0] = f2bf(v.x); d[1] = f2bf(v.y); d[2] = f2bf(v.z); d[3] = f2bf(v.w);
    }
    __syncthreads();
    unsigned short* dst = xT + ((size_t)b * HW + (size_t)y * W_) * 64;
    #pragma unroll
    for (int i = 0; i < 4; ++i) {
        const int o    = (t + i * 256) * 8;
        const int xcol = o >> 6;
        const int c0   = o & 63;
        union { bf16x8 v; unsigned short u[8]; } pk;
        #pragma unroll
        for (int j = 0; j < 8; ++j) pk.u[j] = ld[(c0 + j) * 132 + xcol];
        *(bf16x8*)(dst + o) = pk.v;
    }
}

__global__ void prep_weight_fb(const float* __restrict__ w,
                               unsigned short* __restrict__ wt)
{
    const int i = blockIdx.x * 256 + threadIdx.x;
    if (i >= 9 * 64 * 64) return;
    const int k  = i >> 12;
    const int r  = i & 4095;
    const int co = r >> 6;
    const int c  = r & 63;
    wt[i] = f2bf(w[co * KPOS + c * 9 + k]);
}

__global__ __launch_bounds__(256, 4)
void dcn_mfma_nhwc(const unsigned short* __restrict__ xT,
                   const float* __restrict__ offset,
                   const float* __restrict__ mask,
                   const float* __restrict__ bias,
                   const unsigned short* __restrict__ wprep,
                   float* __restrict__ out)
{
    __shared__ unsigned short vP[2][64][72];
    __shared__ unsigned short Wk[2][64][72];
    const int t   = threadIdx.x;
    const int bid = blockIdx.x;
    const int wk  = ((bid & 7) << 7) | (bid >> 3);
    const int xh  = wk & 1;
    const int ho  = (wk >> 1) & 127;
    const int b   = wk >> 8;
    const int cq  = t >> 6;
    const int lane = t & 63;
    const int px_sub = lane >> 4;
    const int c4     = lane & 15;
    f32x4 acc[4];
    #pragma unroll
    for (int i = 0; i < 4; ++i) acc[i] = (f32x4){0.f, 0.f, 0.f, 0.f};
    const unsigned short* xTb = xT + (size_t)b * HW * 64;

    auto stage = [&](int k, int s) {
        int   idxs[4][4];
        float wts [4][4];
        #pragma unroll
        for (int it = 0; it < 4; ++it) {
            const int pl = (cq << 4) | (it << 2) | px_sub;
            const int wo = xh * 64 + pl;
            const int obase = ((b * 18 + 2 * k) * H_ + ho) * W_ + wo;
            const float dy = offset[obase];
            const float dx = offset[obase + HW];
            const float mm = mask[((b * 9 + k) * H_ + ho) * W_ + wo];
            const float py  = dy + (float)(k / 3) + (float)(ho - 1);
            const float pxx = dx + (float)(k % 3) + (float)(wo - 1);
            const float y0f = floorf(py), x0f = floorf(pxx);
            const float wy = py - y0f, wx = pxx - x0f;
            const int y0 = (int)y0f, x0 = (int)x0f;
            const int y1 = y0 + 1,  x1 = x0 + 1;
            const bool vy0 = (y0 >= 0) & (y0 < H_), vy1 = (y1 >= 0) & (y1 < H_);
            const bool vx0 = (x0 >= 0) & (x0 < W_), vx1 = (x1 >= 0) & (x1 < W_);
            const int cy0 = min(max(y0, 0), H_-1), cy1 = min(max(y1, 0), H_-1);
            const int cx0 = min(max(x0, 0), W_-1), cx1 = min(max(x1, 0), W_-1);
            idxs[it][0] = (cy0 * W_ + cx0) << 6;
            idxs[it][1] = (cy0 * W_ + cx1) << 6;
            idxs[it][2] = (cy1 * W_ + cx0) << 6;
            idxs[it][3] = (cy1 * W_ + cx1) << 6;
            wts[it][0] = (vy0 && vx0) ? (1.f - wy) * (1.f - wx) * mm : 0.f;
            wts[it][1] = (vy0 && vx1) ? (1.f - wy) * wx * mm         : 0.f;
            wts[it][2] = (vy1 && vx0) ? wy * (1.f - wx) * mm         : 0.f;
            wts[it][3] = (vy1 && vx1) ? wy * wx * mm                 : 0.f;
        }
        bf16x4 cr[4][4];
        #pragma unroll
        for (int it = 0; it < 4; ++it)
            #pragma unroll
            for (int cn = 0; cn < 4; ++cn)
                cr[it][cn] = *(const bf16x4*)(xTb + idxs[it][cn] + (c4 << 2));
        #pragma unroll
        for (int q = 0; q < 2; ++q) {
            const int j  = q * 2048 + t * 8;
            *(bf16x8*)&Wk[s][j >> 6][j & 63] = *(const bf16x8*)(wprep + k * 4096 + j);
        }
        #pragma unroll
        for (int it = 0; it < 4; ++it) {
            const int pl = (cq << 4) | (it << 2) | px_sub;
            union { bf16x4 v; unsigned short u[4]; } pk;
            #pragma unroll
            for (int j = 0; j < 4; ++j) {
                union { short s; unsigned short u; } s0{cr[it][0][j]}, s1{cr[it][1][j]},
                                                     s2{cr[it][2][j]}, s3{cr[it][3][j]};
                const float v = wts[it][0] * bfl(s0.u) + wts[it][1] * bfl(s1.u)
                              + wts[it][2] * bfl(s2.u) + wts[it][3] * bfl(s3.u);
                pk.u[j] = f2bf(v);
            }
            *(bf16x4*)&vP[s][pl][c4 << 2] = pk.v;
        }
    };
    auto domfma = [&](int s) {
        const int ra = cq * 16 + (lane & 15);
        const int kc = (lane >> 4) * 8;
        #pragma unroll
        for (int ks = 0; ks < 2; ++ks) {
            const int kcol = ks * 32 + kc;
            const bf16x8 a = *(const bf16x8*)&vP[s][ra][kcol];
            #pragma unroll
            for (int nt = 0; nt < 4; ++nt) {
                const bf16x8 bb = *(const bf16x8*)&Wk[s][nt * 16 + (lane & 15)][kcol];
                acc[nt] = __builtin_amdgcn_mfma_f32_16x16x32_bf16(a, bb, acc[nt], 0, 0, 0);
            }
        }
    };
    stage(0, 0);
    __syncthreads();
    for (int k = 0; k < 9; ++k) {
        const int s = k & 1;
        if (k < 8) stage(k + 1, s ^ 1);
        domfma(s);
        __syncthreads();
    }
    const int px0 = cq * 16 + (lane >> 4) * 4;
    #pragma unroll
    for (int nt = 0; nt < 4; ++nt) {
        const int co = nt * 16 + (lane & 15);
        const float bb = bias[co];
        float4 r;
        r.x = acc[nt][0] + bb;
        r.y = acc[nt][1] + bb;
        r.z = acc[nt][2] + bb;
        r.w = acc[nt][3] + bb;
        *(float4*)&out[(((size_t)b * COUT_ + co) * H_ + ho) * W_ + xh * 64 + px0] = r;
    }
}

extern "C" void kernel_launch(void* const* d_in, const int* in_sizes, int n_in,
                              void* d_out, int out_size, void* d_ws, size_t ws_size,
                              hipStream_t stream)
{
    const float* x      = (const float*)d_in[0];
    const float* offset = (const float*)d_in[1];
    const float* mask   = (const float*)d_in[2];
    const float* weight = (const float*)d_in[3];
    const float* bias   = (const float*)d_in[4];
    float* out = (float*)d_out;

    dim3 block(256);
    dim3 grid(B_ * H_ * 2);

    if (ws_size >= WS_NEED3) {
        _Float16* xT    = (_Float16*)d_ws;
        _Float16* wprep = xT + XT_HALFS;
        unsigned* mOffs = (unsigned*)((char*)d_ws + OFFS_BYTE);
        f16x4*    mWts  = (f16x4*)  ((char*)d_ws + WTS_BYTE);
        prep_all<<<dim3(2960), block, 0, stream>>>(x, offset, mask, weight,
                                                   xT, wprep, mOffs, mWts);
        dcn_f16<<<grid, block, 0, stream>>>(xT, mOffs, mWts, bias, wprep, out);
    } else {
        unsigned short* xTb   = (unsigned short*)d_ws;
        unsigned short* wprep = xTb + XT_HALFS;
        xpose_bf16<<<dim3(B_ * H_), block, 0, stream>>>(x, xTb);
        prep_weight_fb<<<dim3(144), block, 0, stream>>>(weight, wprep);
        dcn_mfma_nhwc<<<grid, block, 0, stream>>>(xTb, offset, mask, bias, wprep, out);
    }
}